// Round 4
// baseline (382.901 us; speedup 1.0000x reference)
//
#include <hip/hip_runtime.h>

// Batched 16-qubit statevector sim. One 1024-thread block per batch element.
// State idx bits: [5:0] = register (64 f32/thread), [11:6] = lane, [15:12] = wave.
// Qubit q <-> idx bit (15-q)  (JAX reshape convention: qubit 0 is MSB).
//
// CNOT staircase handled by GF(2) relabeling (tables = rows/cols of powers of
// the staircase matrix T); only CNOT(12,11) and CNOT(6,5) move data.
// Tables hand-verified r1.
//
// R2 change (unmeasured — GPU timeout r3, resubmitted): __launch_bounds__(1024, 4).
// Baseline compiled to VGPR=64 (compiler defaulted to 8 waves/EU) -> st[64]
// spilled to scratch -> 722 MB HBM traffic per dispatch, VALUBusy 25%, 350 us.
// A 1024-thread block = 16 waves/CU requires <=128 VGPR to be resident at all;
// LDS (132KB) caps at 1 block/CU = 4 waves/EU. (1024,4) sets exactly that
// budget so st[] stays in registers.

__device__ __constant__ unsigned char WM[4][4] = {
  {0x1,0x2,0x4,0x8},{0x1,0x3,0x6,0xC},{0x1,0x2,0x5,0xA},{0x1,0x3,0x7,0xF}};
__device__ __constant__ unsigned char WS[4][4] = {
  {0x1,0x2,0x4,0x8},{0xF,0xE,0xC,0x8},{0x5,0xA,0x4,0x8},{0x3,0x6,0xC,0x8}};
__device__ __constant__ unsigned char LM[4][6] = {
  {0x01,0x02,0x04,0x08,0x10,0x20},
  {0x01,0x03,0x06,0x0C,0x18,0x30},
  {0x01,0x02,0x05,0x0A,0x14,0x28},
  {0x01,0x03,0x07,0x0F,0x1E,0x3C}};
__device__ __constant__ unsigned char LS[4][6] = {
  {0x01,0x02,0x04,0x08,0x10,0x20},
  {0x3F,0x3E,0x3C,0x38,0x30,0x20},
  {0x15,0x2A,0x14,0x28,0x10,0x20},
  {0x33,0x26,0x0C,0x18,0x30,0x20}};
__device__ __constant__ unsigned char WC[4]   = {0xF,0x5,0x3,0x1};
__device__ __constant__ unsigned char TM11[4] = {0x20,0x30,0x28,0x3C};
__device__ __constant__ unsigned char LC[4]   = {0x3F,0x15,0x33,0x11};

__global__ __launch_bounds__(1024, 4)
void qsim_kernel(const float* __restrict__ x, const float* __restrict__ wts,
                 float* __restrict__ out) {
  // 128 KB exchange buffer (one 32-reg chunk for all 16 waves) + angle table.
  __shared__ float2 xbuf[16][16][64];   // [wave][float2-slot][lane]
  __shared__ float2 ang[80];            // [0..15]: x RYs; [16+16l+q]: layer l

  const int tid   = threadIdx.x;
  const int lane  = tid & 63;
  const int wv    = tid >> 6;
  const int batch = blockIdx.x;

  if (tid < 80) {
    float th = (tid < 16) ? x[batch * 16 + tid] : wts[tid - 16];
    float s, c;
    sincosf(0.5f * th, &s, &c);
    ang[tid] = make_float2(c, s);
  }
  __syncthreads();

  float st[64];

  // ---- init: product state |psi> = ⊗_q (c_q|0> + s_q|1>) ----
  {
    float f = 1.0f;
#pragma unroll
    for (int b = 0; b < 4; ++b) { float2 a = ang[3 - b]; f *= ((wv   >> b) & 1) ? a.y : a.x; }
#pragma unroll
    for (int e = 0; e < 6; ++e) { float2 a = ang[9 - e]; f *= ((lane >> e) & 1) ? a.y : a.x; }
    st[0] = f;
#pragma unroll
    for (int k = 0; k < 6; ++k) {
      float2 a = ang[15 - k];
      const int m = 1 << k;
#pragma unroll
      for (int r = 0; r < (1 << k); ++r) {
        st[r + m] = st[r] * a.y;
        st[r]     = st[r] * a.x;
      }
    }
  }

  for (int l = 0; l < 4; ++l) {
    const float2* la = &ang[16 + l * 16];

    // ---- RY on reg bits k=0..5 (qubit 15-k): pure VALU ----
#pragma unroll
    for (int k = 0; k < 6; ++k) {
      const float2 a = la[15 - k];
      const int m = 1 << k;
#pragma unroll
      for (int r = 0; r < 64; ++r) {
        if (!(r & m)) {
          float s0 = st[r], s1 = st[r + m];
          st[r]     = a.x * s0 - a.y * s1;
          st[r + m] = a.y * s0 + a.x * s1;
        }
      }
    }

    // ---- RY on lane bits e=0..5 (qubit 9-e): shfl_xor ----
    for (int e = 0; e < 6; ++e) {
      const float2 a = la[9 - e];
      const int m = LM[l][e];
      const float sg = (__popc(lane & LS[l][e]) & 1) ? a.y : -a.y;
#pragma unroll
      for (int r = 0; r < 64; ++r) {
        float o = __shfl_xor(st[r], m);
        st[r] = fmaf(sg, o, a.x * st[r]);
      }
    }

    // ---- RY on wave bits b=0..3 (qubit 3-b): LDS exchange, 2 chunks ----
    for (int b = 0; b < 4; ++b) {
      const float2 a = la[3 - b];
      const int pw = wv ^ WM[l][b];
      const float sg = (__popc(wv & WS[l][b]) & 1) ? a.y : -a.y;
#pragma unroll
      for (int ch = 0; ch < 2; ++ch) {
        const int base = ch * 32;
        __syncthreads();                         // buffer free (prev reads done)
#pragma unroll
        for (int k2 = 0; k2 < 16; ++k2)
          xbuf[wv][k2][lane] = make_float2(st[base + 2*k2], st[base + 2*k2 + 1]);
        __syncthreads();
#pragma unroll
        for (int k2 = 0; k2 < 16; ++k2) {
          float2 o = xbuf[pw][k2][lane];
          st[base + 2*k2]     = fmaf(sg, o.x, a.x * st[base + 2*k2]);
          st[base + 2*k2 + 1] = fmaf(sg, o.y, a.x * st[base + 2*k2 + 1]);
        }
      }
    }

    // ---- CNOT staircase ----
    // (15,14),(14,13),(13,12): pure wave relabels -> absorbed into tables.
    // (12,11): ctrl = logical wave bit0 @ T^{l+1}; tgt = logical lane bit5 @ T_L^l
    {
      const int tm = TM11[l];
      if (__popc(wv & WC[l]) & 1) {
#pragma unroll
        for (int r = 0; r < 64; ++r) st[r] = __shfl_xor(st[r], tm);
      }
    }
    // (11,10)..(7,6): pure lane relabels -> absorbed.
    // (6,5): ctrl = logical lane bit0 @ T_L^{l+1}; tgt = reg bit5
    {
      const bool cl = (__popc(lane & LC[l]) & 1) != 0;
#pragma unroll
      for (int r = 0; r < 32; ++r) {
        float u = st[r], v = st[r + 32];
        st[r]      = cl ? v : u;
        st[r + 32] = cl ? u : v;
      }
    }
    // (5,4)..(1,0): reg-reg swaps (compile-time renames after unroll)
#pragma unroll
    for (int pc = 5; pc >= 1; --pc) {
      const int cm = 1 << pc, tm2 = 1 << (pc - 1);
#pragma unroll
      for (int r = 0; r < 64; ++r) {
        if ((r & cm) && !(r & tm2)) {
          float t = st[r]; st[r] = st[r + tm2]; st[r + tm2] = t;
        }
      }
    }
  }

  // Output: logical idx 0..15 == physical wave 0 (lambda linear), lane 0, regs 0..15.
  if (tid == 0) {
#pragma unroll
    for (int j = 0; j < 16; ++j) out[batch * 16 + j] = st[j];
  }
}

extern "C" void kernel_launch(void* const* d_in, const int* in_sizes, int n_in,
                              void* d_out, int out_size, void* d_ws, size_t ws_size,
                              hipStream_t stream) {
  const float* x   = (const float*)d_in[0];
  const float* wts = (const float*)d_in[1];
  float* out = (float*)d_out;
  const int batch = in_sizes[0] / 16;   // 512
  qsim_kernel<<<dim3(batch), dim3(1024), 0, stream>>>(x, wts, out);
}

// Round 10
// 381.930 us; speedup vs baseline: 1.0025x; 1.0025x over previous
//
#include <hip/hip_runtime.h>

// Batched 16-qubit statevector sim. One 1024-thread block per batch element.
// State idx bits: [5:0] = register (64 f32/thread), [11:6] = lane, [15:12] = wave.
// Qubit q <-> idx bit (15-q)  (JAX reshape convention: qubit 0 is MSB).
//
// CNOT staircase handled by GF(2) relabeling (tables = rows/cols of powers of
// the staircase matrix T); only CNOT(12,11) and CNOT(6,5) move data.
// Tables hand-verified r1.
//
// R4 finding: __launch_bounds__(1024, 4) was a no-op — VGPR_Count stayed 64,
// 720 MB/dispatch spill traffic, 350 us. The 2nd launch_bounds arg sets only
// the waves-per-eu MINIMUM; the RA heuristic still targeted 8 waves/EU (64-reg
// budget) and spilled st[64] to scratch to get occupancy that LDS (132 KB ->
// 1 block/CU = 4 waves/EU) makes unreachable anyway.
// R5 change (still unmeasured — infra failures r5..r9, resubmitted):
// amdgpu_waves_per_eu(4,4). min=max=4 clamps the RA occupancy target ->
// 128-VGPR budget -> st[] stays in registers, no scratch. 1024-thread block =
// 16 waves needs <=128 VGPR to be resident; LDS pins 1 block/CU anyway, so
// nothing is sacrificed. Decision gate on next successful measurement:
// VGPR ~128 -> spill gone, tune from there; VGPR still 64 -> plan B
// (32 regs/thread + LDS-resident half-state fitting the 64-reg budget).

__device__ __constant__ unsigned char WM[4][4] = {
  {0x1,0x2,0x4,0x8},{0x1,0x3,0x6,0xC},{0x1,0x2,0x5,0xA},{0x1,0x3,0x7,0xF}};
__device__ __constant__ unsigned char WS[4][4] = {
  {0x1,0x2,0x4,0x8},{0xF,0xE,0xC,0x8},{0x5,0xA,0x4,0x8},{0x3,0x6,0xC,0x8}};
__device__ __constant__ unsigned char LM[4][6] = {
  {0x01,0x02,0x04,0x08,0x10,0x20},
  {0x01,0x03,0x06,0x0C,0x18,0x30},
  {0x01,0x02,0x05,0x0A,0x14,0x28},
  {0x01,0x03,0x07,0x0F,0x1E,0x3C}};
__device__ __constant__ unsigned char LS[4][6] = {
  {0x01,0x02,0x04,0x08,0x10,0x20},
  {0x3F,0x3E,0x3C,0x38,0x30,0x20},
  {0x15,0x2A,0x14,0x28,0x10,0x20},
  {0x33,0x26,0x0C,0x18,0x30,0x20}};
__device__ __constant__ unsigned char WC[4]   = {0xF,0x5,0x3,0x1};
__device__ __constant__ unsigned char TM11[4] = {0x20,0x30,0x28,0x3C};
__device__ __constant__ unsigned char LC[4]   = {0x3F,0x15,0x33,0x11};

__global__ __launch_bounds__(1024)
__attribute__((amdgpu_waves_per_eu(4, 4)))
void qsim_kernel(const float* __restrict__ x, const float* __restrict__ wts,
                 float* __restrict__ out) {
  // 128 KB exchange buffer (one 32-reg chunk for all 16 waves) + angle table.
  __shared__ float2 xbuf[16][16][64];   // [wave][float2-slot][lane]
  __shared__ float2 ang[80];            // [0..15]: x RYs; [16+16l+q]: layer l

  const int tid   = threadIdx.x;
  const int lane  = tid & 63;
  const int wv    = tid >> 6;
  const int batch = blockIdx.x;

  if (tid < 80) {
    float th = (tid < 16) ? x[batch * 16 + tid] : wts[tid - 16];
    float s, c;
    sincosf(0.5f * th, &s, &c);
    ang[tid] = make_float2(c, s);
  }
  __syncthreads();

  float st[64];

  // ---- init: product state |psi> = ⊗_q (c_q|0> + s_q|1>) ----
  {
    float f = 1.0f;
#pragma unroll
    for (int b = 0; b < 4; ++b) { float2 a = ang[3 - b]; f *= ((wv   >> b) & 1) ? a.y : a.x; }
#pragma unroll
    for (int e = 0; e < 6; ++e) { float2 a = ang[9 - e]; f *= ((lane >> e) & 1) ? a.y : a.x; }
    st[0] = f;
#pragma unroll
    for (int k = 0; k < 6; ++k) {
      float2 a = ang[15 - k];
      const int m = 1 << k;
#pragma unroll
      for (int r = 0; r < (1 << k); ++r) {
        st[r + m] = st[r] * a.y;
        st[r]     = st[r] * a.x;
      }
    }
  }

  for (int l = 0; l < 4; ++l) {
    const float2* la = &ang[16 + l * 16];

    // ---- RY on reg bits k=0..5 (qubit 15-k): pure VALU ----
#pragma unroll
    for (int k = 0; k < 6; ++k) {
      const float2 a = la[15 - k];
      const int m = 1 << k;
#pragma unroll
      for (int r = 0; r < 64; ++r) {
        if (!(r & m)) {
          float s0 = st[r], s1 = st[r + m];
          st[r]     = a.x * s0 - a.y * s1;
          st[r + m] = a.y * s0 + a.x * s1;
        }
      }
    }

    // ---- RY on lane bits e=0..5 (qubit 9-e): shfl_xor ----
    for (int e = 0; e < 6; ++e) {
      const float2 a = la[9 - e];
      const int m = LM[l][e];
      const float sg = (__popc(lane & LS[l][e]) & 1) ? a.y : -a.y;
#pragma unroll
      for (int r = 0; r < 64; ++r) {
        float o = __shfl_xor(st[r], m);
        st[r] = fmaf(sg, o, a.x * st[r]);
      }
    }

    // ---- RY on wave bits b=0..3 (qubit 3-b): LDS exchange, 2 chunks ----
    for (int b = 0; b < 4; ++b) {
      const float2 a = la[3 - b];
      const int pw = wv ^ WM[l][b];
      const float sg = (__popc(wv & WS[l][b]) & 1) ? a.y : -a.y;
#pragma unroll
      for (int ch = 0; ch < 2; ++ch) {
        const int base = ch * 32;
        __syncthreads();                         // buffer free (prev reads done)
#pragma unroll
        for (int k2 = 0; k2 < 16; ++k2)
          xbuf[wv][k2][lane] = make_float2(st[base + 2*k2], st[base + 2*k2 + 1]);
        __syncthreads();
#pragma unroll
        for (int k2 = 0; k2 < 16; ++k2) {
          float2 o = xbuf[pw][k2][lane];
          st[base + 2*k2]     = fmaf(sg, o.x, a.x * st[base + 2*k2]);
          st[base + 2*k2 + 1] = fmaf(sg, o.y, a.x * st[base + 2*k2 + 1]);
        }
      }
    }

    // ---- CNOT staircase ----
    // (15,14),(14,13),(13,12): pure wave relabels -> absorbed into tables.
    // (12,11): ctrl = logical wave bit0 @ T^{l+1}; tgt = logical lane bit5 @ T_L^l
    {
      const int tm = TM11[l];
      if (__popc(wv & WC[l]) & 1) {
#pragma unroll
        for (int r = 0; r < 64; ++r) st[r] = __shfl_xor(st[r], tm);
      }
    }
    // (11,10)..(7,6): pure lane relabels -> absorbed.
    // (6,5): ctrl = logical lane bit0 @ T_L^{l+1}; tgt = reg bit5
    {
      const bool cl = (__popc(lane & LC[l]) & 1) != 0;
#pragma unroll
      for (int r = 0; r < 32; ++r) {
        float u = st[r], v = st[r + 32];
        st[r]      = cl ? v : u;
        st[r + 32] = cl ? u : v;
      }
    }
    // (5,4)..(1,0): reg-reg swaps (compile-time renames after unroll)
#pragma unroll
    for (int pc = 5; pc >= 1; --pc) {
      const int cm = 1 << pc, tm2 = 1 << (pc - 1);
#pragma unroll
      for (int r = 0; r < 64; ++r) {
        if ((r & cm) && !(r & tm2)) {
          float t = st[r]; st[r] = st[r + tm2]; st[r + tm2] = t;
        }
      }
    }
  }

  // Output: logical idx 0..15 == physical wave 0 (lambda linear), lane 0, regs 0..15.
  if (tid == 0) {
#pragma unroll
    for (int j = 0; j < 16; ++j) out[batch * 16 + j] = st[j];
  }
}

extern "C" void kernel_launch(void* const* d_in, const int* in_sizes, int n_in,
                              void* d_out, int out_size, void* d_ws, size_t ws_size,
                              hipStream_t stream) {
  const float* x   = (const float*)d_in[0];
  const float* wts = (const float*)d_in[1];
  float* out = (float*)d_out;
  const int batch = in_sizes[0] / 16;   // 512
  qsim_kernel<<<dim3(batch), dim3(1024), 0, stream>>>(x, wts, out);
}